// Round 1
// baseline (301.709 us; speedup 1.0000x reference)
//
#include <hip/hip_runtime.h>
#include <hip/hip_bf16.h>

#define D 1024
#define SLEN 2048
#define BS 16
#define MROWS (BS*SLEN)   // 32768

typedef __attribute__((ext_vector_type(8))) short short8;
typedef __attribute__((ext_vector_type(4))) float f32x4;

__device__ __forceinline__ short f2bf(float f) {
  __hip_bfloat16 h = __float2bfloat16(f);
  return __builtin_bit_cast(short, h);
}

// non-temporal float4 load: states is pure streaming in the GEMM (zero reuse
// there) -> bypass L2/L3 retention so the 2 MB WkT stays L2-resident for B.
__device__ __forceinline__ float4 ntload4(const float* p) {
  f32x4 v = __builtin_nontemporal_load((const f32x4*)p);
  float4 r; r.x = v.x; r.y = v.y; r.z = v.z; r.w = v.w; return r;
}

// ---------------- Kernel 1: Wk (k,n) fp32 -> blocked bf16 WkT ----------------
// WkT[(u*1024 + n)*8 + j] = bf16(Wk[(u*8+j)*1024 + n]), u=0..127.
// 16B slot (u,n) = B[n][k=u*8..u*8+7] = one MFMA B k-unit.
__global__ __launch_bounds__(256) void wk_prep(const float* __restrict__ Wk,
                                               short* __restrict__ WkT) {
  const int g = blockIdx.x;        // 0..127
  const int t = threadIdx.x;
#pragma unroll
  for (int it = 0; it < 4; ++it) {
    const int n = it*256 + t;
    short8 p;
#pragma unroll
    for (int j = 0; j < 8; ++j)
      p[j] = f2bf(Wk[(size_t)(g*8 + j)*D + n]);
    *(short8*)(WkT + ((size_t)g*D + n)*8) = p;
  }
}

// ---------------- Kernel 2: energy GEMM, barrier-free K-loop ----------------
// Block = 64 M-rows x full K in LDS (staged once, bf16, padded row stride 129
// slots). 8 waves x 128 cols cover N=1024 -> complete e rows, no atomics.
// B streamed L2->registers, prefetched 1 k-step ahead, no barriers in K-loop.
// A staged with NON-TEMPORAL loads (streaming) to protect WkT's L2 residency.
// Blocks 0..15 also zero-init the attn output (consumed by attn_accum).
__global__ __launch_bounds__(512, 2) void energy_gemm(
    const float* __restrict__ states, const short* __restrict__ WkT,
    const float* __restrict__ bk, const float* __restrict__ We,
    float* __restrict__ eraw, float* __restrict__ attn)
{
  __shared__ short Al[64 * 129 * 8];   // 132 KB: slot(row,u) = row*129 + u

  const int tid  = threadIdx.x;
  const int w    = tid >> 6;        // wave 0..7 -> col group w*128
  const int lane = tid & 63;
  const int quad = lane >> 4;       // k-unit within 32-chunk
  const int l16  = lane & 15;
  const int m0   = blockIdx.x * 64;

  // zero-init attn region (read-modify-write target of attn_accum)
  if (blockIdx.x < BS && tid < 256) {
    f32x4 z = {0.f, 0.f, 0.f, 0.f};
    *(f32x4*)(attn + (size_t)blockIdx.x*D + tid*4) = z;
  }

  // ---- one-time A staging: 64 rows x 1024 k, fp32 -> bf16 (non-temporal) ----
  {
    const int row = tid >> 3;
    const int u0  = tid & 7;
    const float* Ag = states + (size_t)(m0 + row)*D;
#pragma unroll
    for (int i = 0; i < 16; ++i) {
      const int u = u0 + i*8;
      float4 x0 = ntload4(Ag + u*8);
      float4 x1 = ntload4(Ag + u*8 + 4);
      short8 p;
      p[0]=f2bf(x0.x); p[1]=f2bf(x0.y); p[2]=f2bf(x0.z); p[3]=f2bf(x0.w);
      p[4]=f2bf(x1.x); p[5]=f2bf(x1.y); p[6]=f2bf(x1.z); p[7]=f2bf(x1.w);
      *(short8*)(Al + ((size_t)row*129 + u)*8) = p;
    }
  }
  __syncthreads();

  f32x4 acc[2][4][4];
#pragma unroll
  for (int nc = 0; nc < 2; ++nc)
#pragma unroll
    for (int mi = 0; mi < 4; ++mi)
#pragma unroll
      for (int ni = 0; ni < 4; ++ni)
        acc[nc][mi][ni] = (f32x4){0.f, 0.f, 0.f, 0.f};

  const short* bbase = WkT + ((size_t)quad*D + w*128 + l16)*8;   // + ks*32768 + nc*512 + ni*128
  const short* abase = Al + ((size_t)l16*129 + quad)*8;          // + mi*16512 + ks*32

#define LOADB(ks, buf)                                                   \
  {                                                                      \
    const short* bp = bbase + (size_t)(ks)*32768;                        \
    _Pragma("unroll")                                                    \
    for (int nc = 0; nc < 2; ++nc)                                       \
      _Pragma("unroll")                                                  \
      for (int ni = 0; ni < 4; ++ni)                                     \
        buf[nc*4 + ni] = *(const short8*)(bp + nc*512 + ni*128);         \
  }

#define LOADA(ks, buf)                                                   \
  {                                                                      \
    _Pragma("unroll")                                                    \
    for (int mi = 0; mi < 4; ++mi)                                       \
      buf[mi] = *(const short8*)(abase + mi*16512 + (ks)*32);            \
  }

#define MFMAS(fa, fb)                                                    \
  {                                                                      \
    _Pragma("unroll")                                                    \
    for (int nc = 0; nc < 2; ++nc)                                       \
      _Pragma("unroll")                                                  \
      for (int mi = 0; mi < 4; ++mi)                                     \
        _Pragma("unroll")                                                \
        for (int ni = 0; ni < 4; ++ni)                                   \
          acc[nc][mi][ni] = __builtin_amdgcn_mfma_f32_16x16x32_bf16(     \
              fa[mi], fb[nc*4 + ni], acc[nc][mi][ni], 0, 0, 0);          \
  }

  short8 fa0[4], fa1[4], fb0[8], fb1[8];
  LOADA(0, fa0); LOADB(0, fb0);
#pragma unroll
  for (int kk = 0; kk < 16; ++kk) {
    LOADA(2*kk + 1, fa1); LOADB(2*kk + 1, fb1);
    MFMAS(fa0, fb0);
    if (kk < 15) { LOADA(2*kk + 2, fa0); LOADB(2*kk + 2, fb0); }
    MFMAS(fa1, fb1);
  }

  // ---- epilogue: esum[row] += tanh(relu(c + bk[n])) * We_k[n] ----
  float esum[16];
#pragma unroll
  for (int q = 0; q < 16; ++q) esum[q] = 0.f;
#pragma unroll
  for (int nc = 0; nc < 2; ++nc)
#pragma unroll
    for (int ni = 0; ni < 4; ++ni) {
      const int n = w*128 + nc*64 + ni*16 + l16;
      const float bkv = bk[n];
      const float wev = We[D + n];
#pragma unroll
      for (int mi = 0; mi < 4; ++mi)
#pragma unroll
        for (int r = 0; r < 4; ++r) {
          float x = acc[nc][mi][ni][r] + bkv;
          x = fmaxf(x, 0.f);
          float ex = __expf(2.f * x);
          float th = 1.f - 2.f/(ex + 1.f);
          esum[mi*4 + r] += th * wev;
        }
    }
#pragma unroll
  for (int dd = 1; dd < 16; dd <<= 1)
#pragma unroll
    for (int q = 0; q < 16; ++q)
      esum[q] += __shfl_xor(esum[q], dd, 64);

  __syncthreads();                    // all waves done reading Al
  float* red = (float*)Al;            // [64 rows][8 waves]
  if (l16 == 0) {
#pragma unroll
    for (int mi = 0; mi < 4; ++mi)
#pragma unroll
      for (int r = 0; r < 4; ++r)
        red[(mi*16 + quad*4 + r)*8 + w] = esum[mi*4 + r];
  }
  __syncthreads();
  if (tid < 64) {
    float s = 0.f;
#pragma unroll
    for (int wi = 0; wi < 8; ++wi) s += red[tid*8 + wi];
    eraw[m0 + tid] = s;
  }
#undef LOADB
#undef LOADA
#undef MFMAS
}

// ---------- Kernel 3: per-batch softmax stats + normalized weights ----------
// One block per batch row: single reduction over the 2048 energies, writes
// the final attn_weights output (also consumed by attn_accum). Replaces the
// 16x-redundant per-chunk reduction of the old fused kernel.
__global__ __launch_bounds__(256) void softmax_w(
    const float* __restrict__ eraw, float* __restrict__ wts)
{
  const int b = blockIdx.x;
  const int t = threadIdx.x;
  __shared__ float red[256];

  float v[8];
  float m = -1e30f;
#pragma unroll
  for (int j = 0; j < 8; ++j) {
    v[j] = eraw[(size_t)b*SLEN + j*256 + t];
    m = fmaxf(m, v[j]);
  }
  red[t] = m; __syncthreads();
  for (int s = 128; s > 0; s >>= 1) {
    if (t < s) red[t] = fmaxf(red[t], red[t+s]);
    __syncthreads();
  }
  m = red[0];
  __syncthreads();

  float e[8];
  float sum = 0.f;
#pragma unroll
  for (int j = 0; j < 8; ++j) { e[j] = __expf(v[j] - m); sum += e[j]; }
  red[t] = sum; __syncthreads();
  for (int s = 128; s > 0; s >>= 1) {
    if (t < s) red[t] += red[t+s];
    __syncthreads();
  }
  const float inv = 1.f / red[0];
#pragma unroll
  for (int j = 0; j < 8; ++j)
    wts[(size_t)b*SLEN + j*256 + t] = e[j] * inv;
}

// --------------- Kernel 4: attn = sum_s w[s] * states[s,:] ------------------
// Grid (sc=32, b=16) x 512 threads = 2 blocks/CU, 16 waves/CU, 4 waves/SIMD
// (launch_bounds caps VGPR at 128 to keep them resident). Each block owns 64
// s-rows; threads split as (d-quad, s-half). The 32-row loop is fully
// unrolled -> ~32 independent float4 loads in flight per wave, CACHED loads
// (states is L3-resident after the GEMM pass) -> BW-saturated second pass.
// LDS-reduce the two s-halves, then 32-contender atomicAdd per output float.
__global__ __launch_bounds__(512, 4) void attn_accum(
    const float* __restrict__ states, const float* __restrict__ wts,
    float* __restrict__ attn)
{
  const int sc = blockIdx.x;        // 0..31 -> rows sc*64 .. sc*64+63
  const int b  = blockIdx.y;        // 0..15
  const int t  = threadIdx.x;
  const int dq = (t & 255) << 2;    // d offset (float4)
  const int ss = t >> 8;            // s-half 0/1

  __shared__ float  wsh[64];
  __shared__ float4 part[256];

  if (t < 64) wsh[t] = wts[(size_t)b*SLEN + sc*64 + t];
  __syncthreads();

  const float* sp = states + ((size_t)b*SLEN + sc*64 + ss*32)*D + dq;
  float ax = 0.f, ay = 0.f, az = 0.f, aw = 0.f;
#pragma unroll
  for (int s = 0; s < 32; ++s) {
    float4 x = *(const float4*)(sp + (size_t)s*D);
    const float wv = wsh[ss*32 + s];
    ax = fmaf(wv, x.x, ax);
    ay = fmaf(wv, x.y, ay);
    az = fmaf(wv, x.z, az);
    aw = fmaf(wv, x.w, aw);
  }

  if (ss) part[t & 255] = (float4){ax, ay, az, aw};
  __syncthreads();
  if (!ss) {
    const float4 o = part[t];
    float* p = attn + (size_t)b*D + dq;
    atomicAdd(p + 0, ax + o.x);
    atomicAdd(p + 1, ay + o.y);
    atomicAdd(p + 2, az + o.z);
    atomicAdd(p + 3, aw + o.w);
  }
}

extern "C" void kernel_launch(void* const* d_in, const int* in_sizes, int n_in,
                              void* d_out, int out_size, void* d_ws, size_t ws_size,
                              hipStream_t stream) {
  // inputs: 0=query 1=states 2=Wq 3=bq 4=Wk 5=bk 6=We 7=be
  // q-path terms are constant per softmax row -> cancel; dead code.
  const float* states = (const float*)d_in[1];
  const float* Wk     = (const float*)d_in[4];
  const float* bk     = (const float*)d_in[5];
  const float* We     = (const float*)d_in[6];
  float* out = (float*)d_out;            // [0:32768) attn_weights, [32768:49152) attn

  short* WkT  = (short*)d_ws;                                   // 2 MB
  float* eraw = (float*)((char*)d_ws + (size_t)D*D*sizeof(short));  // 128 KB

  (void)in_sizes; (void)n_in; (void)out_size; (void)ws_size;

  wk_prep<<<128, 256, 0, stream>>>(Wk, WkT);
  energy_gemm<<<MROWS/64, 512, 0, stream>>>(states, WkT, bk, We, eraw, out + MROWS);
  softmax_w<<<BS, 256, 0, stream>>>(eraw, out);
  attn_accum<<<dim3(32, BS), 512, 0, stream>>>(states, out, out + MROWS);
}

// Round 2
// 301.499 us; speedup vs baseline: 1.0007x; 1.0007x over previous
//
#include <hip/hip_runtime.h>
#include <hip/hip_bf16.h>

#define D 1024
#define SLEN 2048
#define BS 16
#define MROWS (BS*SLEN)   // 32768

typedef __attribute__((ext_vector_type(8))) short short8;
typedef __attribute__((ext_vector_type(4))) float f32x4;

__device__ __forceinline__ short f2bf(float f) {
  __hip_bfloat16 h = __float2bfloat16(f);
  return __builtin_bit_cast(short, h);
}

// non-temporal float4 load: states is pure streaming in the GEMM (zero reuse
// there) -> bypass L2/L3 retention so the 2 MB WkT stays L2-resident for B.
__device__ __forceinline__ float4 ntload4(const float* p) {
  f32x4 v = __builtin_nontemporal_load((const f32x4*)p);
  float4 r; r.x = v.x; r.y = v.y; r.z = v.z; r.w = v.w; return r;
}

// ---------------- Kernel 1: Wk (k,n) fp32 -> blocked bf16 WkT ----------------
// WkT[(u*1024 + n)*8 + j] = bf16(Wk[(u*8+j)*1024 + n]), u=0..127.
// 16B slot (u,n) = B[n][k=u*8..u*8+7] = one MFMA B k-unit.
__global__ __launch_bounds__(256) void wk_prep(const float* __restrict__ Wk,
                                               short* __restrict__ WkT) {
  const int g = blockIdx.x;        // 0..127
  const int t = threadIdx.x;
#pragma unroll
  for (int it = 0; it < 4; ++it) {
    const int n = it*256 + t;
    short8 p;
#pragma unroll
    for (int j = 0; j < 8; ++j)
      p[j] = f2bf(Wk[(size_t)(g*8 + j)*D + n]);
    *(short8*)(WkT + ((size_t)g*D + n)*8) = p;
  }
}

// ---------------- Kernel 2: energy GEMM, barrier-free K-loop ----------------
// Block = 64 M-rows x full K in LDS (staged once, bf16, padded row stride 129
// slots). 8 waves; each wave now covers its 128 cols in TWO 64-col passes:
// halved acc (64 regs) buys a 3-deep B prefetch ring (3 x 77cyc MFMA cover
// >= ~200cyc L2 latency) -- attacks the vmcnt stall behind MfmaUtil=30%.
// s_setprio(1) around MFMA clusters (waves are independent here, the regime
// where setprio pays). Blocks 0..15 also zero-init the attn output.
__global__ __launch_bounds__(512, 2) void energy_gemm(
    const float* __restrict__ states, const short* __restrict__ WkT,
    const float* __restrict__ bk, const float* __restrict__ We,
    float* __restrict__ eraw, float* __restrict__ attn)
{
  __shared__ short Al[64 * 129 * 8];   // 132 KB: slot(row,u) = row*129 + u

  const int tid  = threadIdx.x;
  const int w    = tid >> 6;        // wave 0..7 -> col group w*128
  const int lane = tid & 63;
  const int quad = lane >> 4;       // k-unit within 32-chunk
  const int l16  = lane & 15;
  const int m0   = blockIdx.x * 64;

  // zero-init attn region (read-modify-write target of attn_fused)
  if (blockIdx.x < BS && tid < 256) {
    f32x4 z = {0.f, 0.f, 0.f, 0.f};
    *(f32x4*)(attn + (size_t)blockIdx.x*D + tid*4) = z;
  }

  // ---- one-time A staging: 64 rows x 1024 k, fp32 -> bf16 (non-temporal) ----
  {
    const int row = tid >> 3;
    const int u0  = tid & 7;
    const float* Ag = states + (size_t)(m0 + row)*D;
#pragma unroll
    for (int i = 0; i < 16; ++i) {
      const int u = u0 + i*8;
      float4 x0 = ntload4(Ag + u*8);
      float4 x1 = ntload4(Ag + u*8 + 4);
      short8 p;
      p[0]=f2bf(x0.x); p[1]=f2bf(x0.y); p[2]=f2bf(x0.z); p[3]=f2bf(x0.w);
      p[4]=f2bf(x1.x); p[5]=f2bf(x1.y); p[6]=f2bf(x1.z); p[7]=f2bf(x1.w);
      *(short8*)(Al + ((size_t)row*129 + u)*8) = p;
    }
  }
  __syncthreads();

  const short* bbase = WkT + ((size_t)quad*D + w*128 + l16)*8;  // + np*512 + ks*32768 + ni*128
  const short* abase = Al + ((size_t)l16*129 + quad)*8;         // + mi*16512 + ks*32

  float esum[16];
#pragma unroll
  for (int q = 0; q < 16; ++q) esum[q] = 0.f;

#define LOADB3(ks, slot)                                                 \
  {                                                                      \
    const short* bp = bpass + (size_t)(ks)*32768;                        \
    _Pragma("unroll")                                                    \
    for (int ni = 0; ni < 4; ++ni)                                       \
      fb[slot][ni] = *(const short8*)(bp + ni*128);                      \
  }

#define LOADA(ks, buf)                                                   \
  {                                                                      \
    _Pragma("unroll")                                                    \
    for (int mi = 0; mi < 4; ++mi)                                       \
      buf[mi] = *(const short8*)(abase + mi*16512 + (ks)*32);            \
  }

#define MFMAS16(fa, slot)                                                \
  {                                                                      \
    __builtin_amdgcn_s_setprio(1);                                       \
    _Pragma("unroll")                                                    \
    for (int mi = 0; mi < 4; ++mi)                                       \
      _Pragma("unroll")                                                  \
      for (int ni = 0; ni < 4; ++ni)                                     \
        acc[mi][ni] = __builtin_amdgcn_mfma_f32_16x16x32_bf16(           \
            fa[mi], fb[slot][ni], acc[mi][ni], 0, 0, 0);                 \
    __builtin_amdgcn_s_setprio(0);                                       \
  }

#pragma unroll
  for (int np = 0; np < 2; ++np) {
    const short* bpass = bbase + np*512;

    f32x4 acc[4][4];
#pragma unroll
    for (int mi = 0; mi < 4; ++mi)
#pragma unroll
      for (int ni = 0; ni < 4; ++ni)
        acc[mi][ni] = (f32x4){0.f, 0.f, 0.f, 0.f};

    short8 fb[3][4];
    short8 fa0[4], fa1[4];
    LOADB3(0, 0); LOADB3(1, 1); LOADB3(2, 2);
    LOADA(0, fa0);
#pragma unroll
    for (int kk = 0; kk < 16; ++kk) {
      LOADA(2*kk + 1, fa1);
      MFMAS16(fa0, (2*kk) % 3);
      if (2*kk + 3 < 32) LOADB3(2*kk + 3, (2*kk) % 3);
      if (kk < 15) LOADA(2*kk + 2, fa0);
      MFMAS16(fa1, (2*kk + 1) % 3);
      if (2*kk + 4 < 32) LOADB3(2*kk + 4, (2*kk + 1) % 3);
    }

    // ---- epilogue partial: esum[row] += tanh(relu(c + bk[n])) * We_k[n] ----
#pragma unroll
    for (int ni = 0; ni < 4; ++ni) {
      const int n = w*128 + np*64 + ni*16 + l16;
      const float bkv = bk[n];
      const float wev = We[D + n];
#pragma unroll
      for (int mi = 0; mi < 4; ++mi)
#pragma unroll
        for (int r = 0; r < 4; ++r) {
          float x = acc[mi][ni][r] + bkv;
          x = fmaxf(x, 0.f);
          float ex = __expf(2.f * x);
          float th = 1.f - 2.f/(ex + 1.f);
          esum[mi*4 + r] += th * wev;
        }
    }
  }

#pragma unroll
  for (int dd = 1; dd < 16; dd <<= 1)
#pragma unroll
    for (int q = 0; q < 16; ++q)
      esum[q] += __shfl_xor(esum[q], dd, 64);

  __syncthreads();                    // all waves done reading Al
  float* red = (float*)Al;            // [64 rows][8 waves]
  if (l16 == 0) {
#pragma unroll
    for (int mi = 0; mi < 4; ++mi)
#pragma unroll
      for (int r = 0; r < 4; ++r)
        red[(mi*16 + quad*4 + r)*8 + w] = esum[mi*4 + r];
  }
  __syncthreads();
  if (tid < 64) {
    float s = 0.f;
#pragma unroll
    for (int wi = 0; wi < 8; ++wi) s += red[tid*8 + wi];
    eraw[m0 + tid] = s;
  }
#undef LOADB3
#undef LOADA
#undef MFMAS16
}

// -------- Kernel 3: fused softmax + attn accumulation (one launch) ----------
// Block (sc,b) = 64 s-rows. Redundant full-row softmax reduction (eraw is
// 128 KB, L2-resident; redundancy is ~2us) kills the separate softmax kernel
// and the wts round-trip. Accumulation: 512 thr = (256 d-quads x 2 s-halves),
// 32 fully-unrolled independent float4 loads per wave, cached loads, LDS
// combine of the halves, 32-contender atomicAdd.
__global__ __launch_bounds__(512) void attn_fused(
    const float* __restrict__ states, const float* __restrict__ eraw,
    float* __restrict__ wts, float* __restrict__ attn)
{
  const int sc = blockIdx.x;        // 0..31 -> rows sc*64 .. sc*64+63
  const int b  = blockIdx.y;        // 0..15
  const int t  = threadIdx.x;
  const int wv = t >> 6;
  const int lane = t & 63;

  __shared__ float  redm[8];
  __shared__ float  reds[8];
  __shared__ float  wsh[64];
  __shared__ float4 part[256];

  // ---- redundant softmax stats over the full 2048-row energy ----
  float v[4];
  float m = -1e30f;
#pragma unroll
  for (int j = 0; j < 4; ++j) {
    v[j] = eraw[(size_t)b*SLEN + j*512 + t];
    m = fmaxf(m, v[j]);
  }
#pragma unroll
  for (int dd = 1; dd < 64; dd <<= 1) m = fmaxf(m, __shfl_xor(m, dd, 64));
  if (lane == 0) redm[wv] = m;
  __syncthreads();
  float m2 = redm[0];
#pragma unroll
  for (int i = 1; i < 8; ++i) m2 = fmaxf(m2, redm[i]);

  float sum = 0.f;
#pragma unroll
  for (int j = 0; j < 4; ++j) sum += __expf(v[j] - m2);
#pragma unroll
  for (int dd = 1; dd < 64; dd <<= 1) sum += __shfl_xor(sum, dd, 64);
  if (lane == 0) reds[wv] = sum;
  __syncthreads();
  float s2 = 0.f;
#pragma unroll
  for (int i = 0; i < 8; ++i) s2 += reds[i];
  const float inv = 1.f / s2;

  // ---- weights for this block's 64 rows ----
  if (t < 64) {
    const float wvv = __expf(eraw[(size_t)b*SLEN + sc*64 + t] - m2) * inv;
    wts[(size_t)b*SLEN + sc*64 + t] = wvv;
    wsh[t] = wvv;
  }
  __syncthreads();

  // ---- accumulate attn partial ----
  const int dq = (t & 255) << 2;    // d offset (float4)
  const int ss = t >> 8;            // s-half 0/1
  const float* sp = states + ((size_t)b*SLEN + sc*64 + ss*32)*D + dq;
  float ax = 0.f, ay = 0.f, az = 0.f, aw = 0.f;
#pragma unroll
  for (int s = 0; s < 32; ++s) {
    float4 x = *(const float4*)(sp + (size_t)s*D);
    const float wvv = wsh[ss*32 + s];
    ax = fmaf(wvv, x.x, ax);
    ay = fmaf(wvv, x.y, ay);
    az = fmaf(wvv, x.z, az);
    aw = fmaf(wvv, x.w, aw);
  }

  if (ss) part[t & 255] = (float4){ax, ay, az, aw};
  __syncthreads();
  if (!ss) {
    const float4 o = part[t];
    float* p = attn + (size_t)b*D + dq;
    atomicAdd(p + 0, ax + o.x);
    atomicAdd(p + 1, ay + o.y);
    atomicAdd(p + 2, az + o.z);
    atomicAdd(p + 3, aw + o.w);
  }
}

extern "C" void kernel_launch(void* const* d_in, const int* in_sizes, int n_in,
                              void* d_out, int out_size, void* d_ws, size_t ws_size,
                              hipStream_t stream) {
  // inputs: 0=query 1=states 2=Wq 3=bq 4=Wk 5=bk 6=We 7=be
  // q-path terms are constant per softmax row -> cancel; dead code.
  const float* states = (const float*)d_in[1];
  const float* Wk     = (const float*)d_in[4];
  const float* bk     = (const float*)d_in[5];
  const float* We     = (const float*)d_in[6];
  float* out = (float*)d_out;            // [0:32768) attn_weights, [32768:49152) attn

  short* WkT  = (short*)d_ws;                                   // 2 MB
  float* eraw = (float*)((char*)d_ws + (size_t)D*D*sizeof(short));  // 128 KB

  (void)in_sizes; (void)n_in; (void)out_size; (void)ws_size;

  wk_prep<<<128, 256, 0, stream>>>(Wk, WkT);
  energy_gemm<<<MROWS/64, 512, 0, stream>>>(states, WkT, bk, We, eraw, out + MROWS);
  attn_fused<<<dim3(32, BS), 512, 0, stream>>>(states, eraw, out, out + MROWS);
}